// Round 12
// baseline (576.418 us; speedup 1.0000x reference)
//
#include <hip/hip_runtime.h>

typedef unsigned short u16;
typedef u16 u16x8 __attribute__((ext_vector_type(8)));
typedef __bf16 bf16x8 __attribute__((ext_vector_type(8)));
typedef float f32x4 __attribute__((ext_vector_type(4)));

#define DEV __device__ __forceinline__
#define MFMA16 __builtin_amdgcn_mfma_f32_16x16x32_bf16

constexpr int Bb = 2, Nctx = 2048, Dm = 512, Hh = 8, Dh = 512, Ff = 4096;
constexpr int Mrows = Bb * Nctx;  // 4096

DEV float b2f(u16 u) { unsigned int i = ((unsigned int)u) << 16; return __builtin_bit_cast(float, i); }
DEV u16 f2b(float f) {
  unsigned int x = __builtin_bit_cast(unsigned int, f);
  return (u16)((x + 0x7FFFu + ((x >> 16) & 1u)) >> 16);
}
DEV bf16x8 ld8(const u16* p) { return __builtin_bit_cast(bf16x8, *(const u16x8*)p); }

// async global->LDS, 16B per lane. LDS dest must be wave-uniform base + lane*16.
DEV void gload16(const u16* g, u16* l) {
#if defined(__has_builtin) && __has_builtin(__builtin_amdgcn_global_load_lds)
  __builtin_amdgcn_global_load_lds((const __attribute__((address_space(1))) void*)(g),
                                   (__attribute__((address_space(3))) void*)(l), 16, 0, 0);
#else
  *(u16x8*)l = *(const u16x8*)g;
#endif
}

// ---------------- f32 -> bf16 convert ----------------
__global__ void convert_k(const float* __restrict__ in, u16* __restrict__ out, int n8) {
  int idx = blockIdx.x * 256 + threadIdx.x;
  if (idx >= n8) return;
  size_t e0 = (size_t)idx * 8;
  f32x4 a = *(const f32x4*)(in + e0);
  f32x4 b = *(const f32x4*)(in + e0 + 4);
  u16x8 o;
  #pragma unroll
  for (int i = 0; i < 4; ++i) { o[i] = f2b(a[i]); o[4 + i] = f2b(b[i]); }
  *(u16x8*)(out + e0) = o;
}

// ---- weight transpose v2: out_bf16[c][r] = in_f32[r][c], 16B both global sides ----
// Round 11: neutral vs 32x32 scalar-store version (launch-bound), kept.
__global__ void transposeW64_k(const float* __restrict__ in, u16* __restrict__ out,
                               int R, int C) {
  __shared__ u16 tile[64 * 64];
  const int c0 = blockIdx.x * 64, r0 = blockIdx.y * 64;
  const int t = threadIdx.x;  // 0..255
  const int rl = t >> 3;      // 0..31
  const int cg = t & 7;       // 8-wide col group
  #pragma unroll
  for (int sw = 0; sw < 2; ++sw) {
    int r = rl + 32 * sw;
    const float* p = in + (size_t)(r0 + r) * C + c0 + cg * 8;
    f32x4 a = *(const f32x4*)p;
    f32x4 b = *(const f32x4*)(p + 4);
    #pragma unroll
    for (int j = 0; j < 8; ++j) {
      int c = cg * 8 + j;
      int g = ((c & 7) ^ (c >> 3)) & 7;
      tile[c * 64 + (r ^ (g << 3))] = f2b(j < 4 ? a[j] : b[j - 4]);
    }
  }
  __syncthreads();
  #pragma unroll
  for (int sw = 0; sw < 2; ++sw) {
    int c = rl + 32 * sw;
    int g = ((c & 7) ^ (c >> 3)) & 7;
    u16x8 v = *(const u16x8*)&tile[c * 64 + ((cg ^ g) << 3)];
    *(u16x8*)&out[(size_t)(c0 + c) * R + r0 + cg * 8] = v;
  }
}

// ---- batched V transpose v2: Vt[bh][d][n] = V[b*N+n][h*Dh+d], 16B both sides ----
// Verified round 7 (rest-side -17us vs round 6, correctness passed 5 rounds).
__global__ void vtrans_k(const u16* __restrict__ V, u16* __restrict__ Vt) {
  __shared__ u16 tile[64 * 64];
  const int z = blockIdx.z;  // b*8+h
  const int b = z >> 3, h = z & 7;
  const int n0 = blockIdx.x * 64, d0 = blockIdx.y * 64;
  const int t = threadIdx.x;  // 0..255
  const int nl = t >> 3;      // 0..31
  const int dg = t & 7;       // 8-wide group
  #pragma unroll
  for (int sw = 0; sw < 2; ++sw) {
    int n = nl + 32 * sw;
    u16x8 v = *(const u16x8*)&V[((size_t)(b * Nctx + n0 + n)) * Ff + h * Dh + d0 + dg * 8];
    #pragma unroll
    for (int j = 0; j < 8; ++j) {
      int d = dg * 8 + j;
      int g = ((d & 7) ^ (d >> 3)) & 7;
      tile[d * 64 + (n ^ (g << 3))] = v[j];
    }
  }
  __syncthreads();
  #pragma unroll
  for (int sw = 0; sw < 2; ++sw) {
    int d = nl + 32 * sw;
    int g = ((d & 7) ^ (d >> 3)) & 7;
    u16x8 v = *(const u16x8*)&tile[d * 64 + ((dg ^ g) << 3)];
    *(u16x8*)&Vt[((size_t)(z * Dh + d0 + d)) * Nctx + n0 + dg * 8] = v;
  }
}

// ------- GEMM 128x128 tile, BK=64, global_load_lds staging, 4 waves 2x2 -------
// Verified rounds 7-11. SEPARATE launches per Q/K/V (round 9: merged -31us).
// MODE: 0 plain->bf16, 1 rope->bf16, 2 bias->bf16, 3 bias->f32
template <int MODE>
__launch_bounds__(256, 4)
__global__ void gemm2_k(const u16* __restrict__ A, const u16* __restrict__ BT,
                        void* __restrict__ Cout, const float* __restrict__ bias,
                        const float* __restrict__ cs, const float* __restrict__ sn,
                        int Ndim, int Kdim) {
  __shared__ u16 sA[128 * 64];
  __shared__ u16 sB[128 * 64];
  const int tid = threadIdx.x;
  const int wave = tid >> 6, lane = tid & 63, quad = lane >> 4, l16 = lane & 15;
  const int wy = wave >> 1, wx = wave & 1;
  const int m0 = blockIdx.y * 128, n0 = blockIdx.x * 128;
  f32x4 acc[4][4];
  #pragma unroll
  for (int i = 0; i < 4; ++i)
    #pragma unroll
    for (int j = 0; j < 4; ++j)
      #pragma unroll
      for (int r = 0; r < 4; ++r) acc[i][j][r] = 0.f;
  const int srow = tid >> 3;        // 0..31 (32 rows per staging sweep)
  const int scol = (tid & 7) * 8;   // 0..56; LDS dest = tid*16B (wave-linear)
  for (int k0 = 0; k0 < Kdim; k0 += 64) {
    __syncthreads();
    #pragma unroll
    for (int sw = 0; sw < 4; ++sw) {
      int row = srow + 32 * sw;
      int sc = scol ^ ((row & 7) * 8);  // pre-swizzled source column
      gload16(A + (size_t)(m0 + row) * Kdim + k0 + sc, &sA[row * 64 + scol]);
      gload16(BT + (size_t)(n0 + row) * Kdim + k0 + sc, &sB[row * 64 + scol]);
    }
    __syncthreads();
    #pragma unroll
    for (int kk2 = 0; kk2 < 2; ++kk2) {
      const int cbase = (kk2 * 32 + quad * 8) ^ ((l16 & 7) * 8);
      bf16x8 af[4], bf[4];
      #pragma unroll
      for (int t = 0; t < 4; ++t) af[t] = ld8(&sA[(wy * 64 + t * 16 + l16) * 64 + cbase]);
      #pragma unroll
      for (int t = 0; t < 4; ++t) bf[t] = ld8(&sB[(wx * 64 + t * 16 + l16) * 64 + cbase]);
      #pragma unroll
      for (int i = 0; i < 4; ++i)
        #pragma unroll
        for (int j = 0; j < 4; ++j)
          acc[i][j] = MFMA16(af[i], bf[j], acc[i][j], 0, 0, 0);
    }
  }
  #pragma unroll
  for (int i = 0; i < 4; ++i) {
    #pragma unroll
    for (int j = 0; j < 4; ++j) {
      int col = n0 + wx * 64 + j * 16 + l16;
      float badd = (MODE == 2 || MODE == 3) ? bias[col] : 0.f;
      #pragma unroll
      for (int r = 0; r < 4; ++r) {
        int row = m0 + wy * 64 + i * 16 + quad * 4 + r;  // C: col=lane&15, row=quad*4+reg
        float v = acc[i][j][r] + badd;
        if (MODE == 1) {  // fused RoPE: pairs (col even, col odd) across lane^1
          float vp = __shfl_xor(v, 1);
          int n = row & (Nctx - 1);
          float c = cs[(size_t)n * Ff + col];
          float s = sn[(size_t)n * Ff + col];
          v = (l16 & 1) ? (v * c + vp * s) : (v * c - vp * s);
        }
        if (MODE == 3) ((float*)Cout)[(size_t)row * Ndim + col] = v;
        else           ((u16*)Cout)[(size_t)row * Ndim + col] = f2b(v);
      }
    }
  }
}

// ---------------- flash attention (causal, unscaled), 2 blocks/CU ----------------
// Round-6/8/10 structure (294-295us, VGPR 256, FETCH 66MB verified 4x) + T13
// defer-max (HK RESCALE_THRESHOLD=8): when the tile's row max grows by <= 8,
// keep the old running max -> alpha == exp(0) == 1.0 exactly. PV then checks
// all 64 alphas (it reads them anyway) and SKIPS the 128-multiply acc rescale
// via a wave-uniform __any branch. P bounded by e^8 (bf16-safe; O is
// scale-invariant; guide m239: data-independent within noise).
// NO setprio (round 7: -33us). Allocator rule: ONLY 4-wave (256,1) gets 256
// VGPR. Schedule: XCD-affine decode; zigzag qt; lockstep ascending jt sweep.
__launch_bounds__(256, 1)
__global__ void attn_k(const u16* __restrict__ Q, const u16* __restrict__ K,
                       const u16* __restrict__ Vt, u16* __restrict__ Yp) {
  __shared__ u16 sK[64 * 512];   // [key][dh], phys chunk16 = (chunk+key)&63
  __shared__ u16 sP[64 * 72];
  __shared__ float sAl[64];
  __shared__ float sL[64];
  const int idx = blockIdx.x;
  const int hi = idx >> 8;
  const int bh = (idx & 7) | (hi << 3);  // XCD-affine: idx%8 pins h per XCD
  const int q_ = (idx >> 3) & 31;
  const int zig = (q_ & 1) ? (31 - (q_ >> 1)) : (q_ >> 1);
  const int qt = hi ? (31 - zig) : zig;  // pairs sum to 33 units in both pairings
  const int b = bh >> 3, h = bh & 7;
  const int q0 = qt * 64;
  const int wave = threadIdx.x >> 6, lane = threadIdx.x & 63;
  const int quad = lane >> 4, l16 = lane & 15;
  const int mq = q0 + wave * 16;  // QK^T rows for this wave
  const int wd = wave * 128;      // PV dh-slice for this wave

  bf16x8 qf[16];
  {
    const u16* qp = Q + ((size_t)(b * Nctx + mq + l16)) * Ff + h * Dh + quad * 8;
    #pragma unroll
    for (int i = 0; i < 16; ++i) qf[i] = ld8(qp + i * 32);
  }
  f32x4 acc[4][8];
  #pragma unroll
  for (int g = 0; g < 4; ++g)
    #pragma unroll
    for (int t = 0; t < 8; ++t)
      #pragma unroll
      for (int r = 0; r < 4; ++r) acc[g][t][r] = 0.f;
  float mrun[4], lrun[4];
  #pragma unroll
  for (int r = 0; r < 4; ++r) { mrun[r] = -__builtin_inff(); lrun[r] = 0.f; }

  auto stageK = [&](int j0) {
    #pragma unroll
    for (int it = 0; it < 16; ++it) {
      int row = wave * 16 + it;
      const u16* gp = K + ((size_t)(b * Nctx + j0 + row)) * Ff + h * Dh + (((lane - row) & 63) * 8);
      gload16(gp, &sK[row * 512 + lane * 8]);
    }
  };
  // V row pointer for this lane's dh rows (l16 selects row within 16-row group)
  const u16* vrow = Vt + ((size_t)(bh * Dh + wd + l16)) * Nctx;

  stageK(0);
  for (int jt = 0; jt <= qt; ++jt) {
    const int j0 = jt * 64;
    __syncthreads();  // K(jt) DMA drained; prev pv's sP reads ordered
    // --- QK^T over 64 keys ---
    f32x4 s[4];
    #pragma unroll
    for (int kg = 0; kg < 4; ++kg)
      #pragma unroll
      for (int r = 0; r < 4; ++r) s[kg][r] = 0.f;
    #pragma unroll
    for (int kk = 0; kk < 16; ++kk) {
      #pragma unroll
      for (int kg = 0; kg < 4; ++kg) {
        int key = kg * 16 + l16;
        bf16x8 bfr = ld8(&sK[key * 512 + (((kk * 4 + quad + key) & 63) * 8)]);
        s[kg] = MFMA16(qf[kk], bfr, s[kg], 0, 0, 0);
      }
    }
    // --- online softmax with defer-max (mask only on diagonal tile) ---
    const bool diag = (jt == qt);
    float p[4][4], alpha[4];
    #pragma unroll
    for (int r = 0; r < 4; ++r) {
      int qrow = mq + quad * 4 + r;
      float sv[4];
      #pragma unroll
      for (int kg = 0; kg < 4; ++kg) {
        int key = j0 + kg * 16 + l16;
        sv[kg] = (diag && key > qrow) ? -__builtin_inff() : s[kg][r];
      }
      float mx = fmaxf(fmaxf(sv[0], sv[1]), fmaxf(sv[2], sv[3]));
      mx = fmaxf(mx, __shfl_xor(mx, 1));
      mx = fmaxf(mx, __shfl_xor(mx, 2));
      mx = fmaxf(mx, __shfl_xor(mx, 4));
      mx = fmaxf(mx, __shfl_xor(mx, 8));
      // T13 defer-max: keep old max unless growth > 8 -> alpha==1.0 exactly
      float mkeep = (mx > mrun[r] + 8.f) ? mx : mrun[r];
      float a = __expf(mrun[r] - mkeep);  // v_exp_f32(0) == 1.0 on defer path
      mrun[r] = mkeep;
      float rs = 0.f;
      #pragma unroll
      for (int kg = 0; kg < 4; ++kg) { float pe = __expf(sv[kg] - mkeep); p[r][kg] = pe; rs += pe; }
      lrun[r] = lrun[r] * a + rs;
      alpha[r] = a;
    }
    #pragma unroll
    for (int r = 0; r < 4; ++r) {
      #pragma unroll
      for (int kg = 0; kg < 4; ++kg)
        sP[(wave * 16 + quad * 4 + r) * 72 + kg * 16 + l16] = f2b(p[r][kg]);
      if (l16 == 0) sAl[wave * 16 + quad * 4 + r] = alpha[r];
    }
    __syncthreads();  // sP/sAl visible; all waves done reading sK(jt)
    if (jt < qt) stageK(j0 + 64);  // async; overlaps PV below; drained at loop top
    // --- PV for this tile: P from sP, V direct from global (L2) ---
    {
      float alr[4][4];
      int need = 0;
      #pragma unroll
      for (int g = 0; g < 4; ++g)
        #pragma unroll
        for (int r = 0; r < 4; ++r) {
          alr[g][r] = sAl[g * 16 + quad * 4 + r];
          need |= (alr[g][r] != 1.f);
        }
      if (__any(need)) {  // wave-uniform: 64 lanes jointly cover all 64 rows
        #pragma unroll
        for (int g = 0; g < 4; ++g)
          #pragma unroll
          for (int t = 0; t < 8; ++t) {
            acc[g][t][0] *= alr[g][0]; acc[g][t][1] *= alr[g][1];
            acc[g][t][2] *= alr[g][2]; acc[g][t][3] *= alr[g][3];
          }
      }
      bf16x8 pf[4][2];
      #pragma unroll
      for (int g = 0; g < 4; ++g)
        #pragma unroll
        for (int kk = 0; kk < 2; ++kk)
          pf[g][kk] = ld8(&sP[(g * 16 + l16) * 72 + kk * 32 + quad * 8]);
      #pragma unroll
      for (int t = 0; t < 8; ++t) {
        const u16* vp = vrow + (size_t)(t * 16) * Nctx + j0 + quad * 8;
        bf16x8 v0 = ld8(vp);
        bf16x8 v1 = ld8(vp + 32);
        #pragma unroll
        for (int g = 0; g < 4; ++g) acc[g][t] = MFMA16(pf[g][0], v0, acc[g][t], 0, 0, 0);
        #pragma unroll
        for (int g = 0; g < 4; ++g) acc[g][t] = MFMA16(pf[g][1], v1, acc[g][t], 0, 0, 0);
      }
    }
  }
  // row sums -> sL
  #pragma unroll
  for (int r = 0; r < 4; ++r) {
    float l = lrun[r];
    l += __shfl_xor(l, 1);
    l += __shfl_xor(l, 2);
    l += __shfl_xor(l, 4);
    l += __shfl_xor(l, 8);
    if (l16 == 0) sL[wave * 16 + quad * 4 + r] = l;
  }
  __syncthreads();
  #pragma unroll
  for (int g = 0; g < 4; ++g) {
    float inv[4];
    #pragma unroll
    for (int r = 0; r < 4; ++r) inv[r] = 1.f / sL[g * 16 + quad * 4 + r];
    #pragma unroll
    for (int t = 0; t < 8; ++t)
      #pragma unroll
      for (int r = 0; r < 4; ++r)
        Yp[((size_t)bh * Nctx + q0 + g * 16 + quad * 4 + r) * Dh + wd + t * 16 + l16] =
            f2b(acc[g][t][r] * inv[r]);
  }
}

// ---------------- head-sum + QuickGELU -> bf16 ----------------
__global__ void sumheads_k(const u16* __restrict__ Yp, u16* __restrict__ Ys) {
  size_t idx = (size_t)blockIdx.x * 256 + threadIdx.x;
  size_t e0 = idx * 8;
  int b = (int)(e0 >> 20);
  size_t rem = e0 & ((1u << 20) - 1);
  float s[8];
  #pragma unroll
  for (int e = 0; e < 8; ++e) s[e] = 0.f;
  #pragma unroll
  for (int h = 0; h < Hh; ++h) {
    u16x8 v = *(const u16x8*)&Yp[((size_t)(b * Hh + h) << 20) + rem];
    #pragma unroll
    for (int e = 0; e < 8; ++e) s[e] += b2f(v[e]);
  }
  u16x8 o;
  #pragma unroll
  for (int e = 0; e < 8; ++e) {
    float g = s[e] / (1.f + __expf(-1.702f * s[e]));
    o[e] = f2b(g);
  }
  *(u16x8*)&Ys[e0] = o;
}

extern "C" void kernel_launch(void* const* d_in, const int* in_sizes, int n_in,
                              void* d_out, int out_size, void* d_ws, size_t ws_size,
                              hipStream_t stream) {
  const float* x  = (const float*)d_in[0];
  const float* cs = (const float*)d_in[1];
  const float* sn = (const float*)d_in[2];
  int wbase = 4;                        // target_mask (bool tril) at idx 3, hard-coded
  if (n_in == 9) wbase = 3;
  if (wbase + 3 < n_in && in_sizes[wbase + 3] != 4096) wbase = (wbase == 4) ? 3 : 4;
  const float* Wq = (const float*)d_in[wbase + 0];
  const float* Wk = (const float*)d_in[wbase + 1];
  const float* Wv = (const float*)d_in[wbase + 2];
  const float* bv = (const float*)d_in[wbase + 3];
  const float* Wo = (const float*)d_in[wbase + 4];
  const float* bo = (const float*)d_in[wbase + 5];

  // ws layout (132.5 MiB), with aliasing:
  //  [0,32M): WqT@0, WkT@4M, WvT@8M, xb@12M  -> later reused as Vt
  //  [32,64M): Qb   [64,96M): Kb   [96,128M): Vb -> later reused as Yp
  //  [128M,+0.5M): WoT   [+0.5M,+4.5M): Ys
  char* ws = (char*)d_ws;
  const size_t MiB = 1ull << 20;
  u16* WqT = (u16*)(ws + 0 * MiB);
  u16* WkT = (u16*)(ws + 4 * MiB);
  u16* WvT = (u16*)(ws + 8 * MiB);
  u16* xb  = (u16*)(ws + 12 * MiB);
  u16* Vt  = (u16*)(ws + 0 * MiB);    // alias: weights/xb dead after QKV gemms
  u16* Qb  = (u16*)(ws + 32 * MiB);
  u16* Kb  = (u16*)(ws + 64 * MiB);
  u16* Vb  = (u16*)(ws + 96 * MiB);
  u16* Yp  = Vb;                      // alias: Vb dead after vtrans
  u16* WoT = (u16*)(ws + 128 * MiB);
  u16* Ys  = (u16*)(ws + 128 * MiB + 512 * 1024);

  transposeW64_k<<<dim3(Ff / 64, Dm / 64), 256, 0, stream>>>(Wq, WqT, Dm, Ff);
  transposeW64_k<<<dim3(Ff / 64, Dm / 64), 256, 0, stream>>>(Wk, WkT, Dm, Ff);
  transposeW64_k<<<dim3(Ff / 64, Dm / 64), 256, 0, stream>>>(Wv, WvT, Dm, Ff);
  transposeW64_k<<<dim3(Dm / 64, Dm / 64), 256, 0, stream>>>(Wo, WoT, Dm, Dm);
  convert_k<<<dim3(Mrows * Dm / 8 / 256), 256, 0, stream>>>(x, xb, Mrows * Dm / 8);

  gemm2_k<1><<<dim3(Ff / 128, Mrows / 128), 256, 0, stream>>>(xb, WqT, Qb, nullptr, cs, sn, Ff, Dm);
  gemm2_k<1><<<dim3(Ff / 128, Mrows / 128), 256, 0, stream>>>(xb, WkT, Kb, nullptr, cs, sn, Ff, Dm);
  gemm2_k<2><<<dim3(Ff / 128, Mrows / 128), 256, 0, stream>>>(xb, WvT, Vb, bv, nullptr, nullptr, Ff, Dm);

  vtrans_k<<<dim3(Nctx / 64, Dh / 64, Bb * Hh), 256, 0, stream>>>(Vb, Vt);

  attn_k<<<dim3(512), 256, 0, stream>>>(Qb, Kb, Vt, Yp);

  sumheads_k<<<dim3(Mrows * Dm / 8 / 256), 256, 0, stream>>>(Yp, Ys);

  gemm2_k<3><<<dim3(Dm / 128, Mrows / 128), 256, 0, stream>>>(Ys, WoT, d_out, bo, nullptr, nullptr, Dm, Dm);
}

// Round 13
// 554.559 us; speedup vs baseline: 1.0394x; 1.0394x over previous
//
#include <hip/hip_runtime.h>

typedef unsigned short u16;
typedef u16 u16x8 __attribute__((ext_vector_type(8)));
typedef __bf16 bf16x8 __attribute__((ext_vector_type(8)));
typedef float f32x4 __attribute__((ext_vector_type(4)));

#define DEV __device__ __forceinline__
#define MFMA16 __builtin_amdgcn_mfma_f32_16x16x32_bf16

constexpr int Bb = 2, Nctx = 2048, Dm = 512, Hh = 8, Dh = 512, Ff = 4096;
constexpr int Mrows = Bb * Nctx;  // 4096

DEV float b2f(u16 u) { unsigned int i = ((unsigned int)u) << 16; return __builtin_bit_cast(float, i); }
DEV u16 f2b(float f) {
  unsigned int x = __builtin_bit_cast(unsigned int, f);
  return (u16)((x + 0x7FFFu + ((x >> 16) & 1u)) >> 16);
}
DEV bf16x8 ld8(const u16* p) { return __builtin_bit_cast(bf16x8, *(const u16x8*)p); }

// async global->LDS, 16B per lane. LDS dest must be wave-uniform base + lane*16.
DEV void gload16(const u16* g, u16* l) {
#if defined(__has_builtin) && __has_builtin(__builtin_amdgcn_global_load_lds)
  __builtin_amdgcn_global_load_lds((const __attribute__((address_space(1))) void*)(g),
                                   (__attribute__((address_space(3))) void*)(l), 16, 0, 0);
#else
  *(u16x8*)l = *(const u16x8*)g;
#endif
}

// ---------------- f32 -> bf16 convert ----------------
__global__ void convert_k(const float* __restrict__ in, u16* __restrict__ out, int n8) {
  int idx = blockIdx.x * 256 + threadIdx.x;
  if (idx >= n8) return;
  size_t e0 = (size_t)idx * 8;
  f32x4 a = *(const f32x4*)(in + e0);
  f32x4 b = *(const f32x4*)(in + e0 + 4);
  u16x8 o;
  #pragma unroll
  for (int i = 0; i < 4; ++i) { o[i] = f2b(a[i]); o[4 + i] = f2b(b[i]); }
  *(u16x8*)(out + e0) = o;
}

// ---------------- transpose + convert: out_bf16[c][r] = in_f32[r][c] ----------------
__global__ void transpose_k(const float* __restrict__ in, u16* __restrict__ out,
                            int rows, int cols) {
  __shared__ float tile[32][33];
  int bx = blockIdx.x * 32, by = blockIdx.y * 32;
  int tx = threadIdx.x, ty = threadIdx.y;
  #pragma unroll
  for (int i = ty; i < 32; i += 8)
    tile[i][tx] = in[(size_t)(by + i) * cols + bx + tx];
  __syncthreads();
  #pragma unroll
  for (int i = ty; i < 32; i += 8)
    out[(size_t)(bx + i) * rows + by + tx] = f2b(tile[tx][i]);
}

// ---- batched V transpose v2: Vt[bh][d][n] = V[b*N+n][h*Dh+d], 16B both sides ----
// 64x64 tile, u16x8 (16B) global load AND store. LDS: [64][64] u16 with XOR
// swizzle col' = n ^ (((d&7)^(d>>3))<<3): write side = scalar u16 2 lanes/bank
// (free, m136); read side = b128 at minimum pass count. Verified round 7
// (rest-side -17us vs round 6, correctness passed 6 rounds).
__global__ void vtrans_k(const u16* __restrict__ V, u16* __restrict__ Vt) {
  __shared__ u16 tile[64 * 64];
  const int z = blockIdx.z;  // b*8+h
  const int b = z >> 3, h = z & 7;
  const int n0 = blockIdx.x * 64, d0 = blockIdx.y * 64;
  const int t = threadIdx.x;  // 0..255
  const int nl = t >> 3;      // 0..31
  const int dg = t & 7;       // 8-wide group
  #pragma unroll
  for (int sw = 0; sw < 2; ++sw) {
    int n = nl + 32 * sw;
    u16x8 v = *(const u16x8*)&V[((size_t)(b * Nctx + n0 + n)) * Ff + h * Dh + d0 + dg * 8];
    #pragma unroll
    for (int j = 0; j < 8; ++j) {
      int d = dg * 8 + j;
      int g = ((d & 7) ^ (d >> 3)) & 7;
      tile[d * 64 + (n ^ (g << 3))] = v[j];
    }
  }
  __syncthreads();
  #pragma unroll
  for (int sw = 0; sw < 2; ++sw) {
    int d = nl + 32 * sw;
    int g = ((d & 7) ^ (d >> 3)) & 7;
    u16x8 v = *(const u16x8*)&tile[d * 64 + ((dg ^ g) << 3)];
    *(u16x8*)&Vt[((size_t)(z * Dh + d0 + d)) * Nctx + n0 + dg * 8] = v;
  }
}

// ------- GEMM 128x128 tile, BK=64, global_load_lds staging, 4 waves 2x2 -------
// BK=64: 32 MFMA per barrier pair, 8 k-steps for K=512. 128B row stride's
// 4-way ds_read conflict fixed by XOR swizzle col' = col ^ ((row&7)*8) applied
// BOTH on the global source column (gload_lds dest stays linear, T21/m173)
// and on the LDS read address. Verified rounds 7-12.
// SEPARATE launches per Q/K/V (round 9: merged launch -31us).
// MODE: 0 plain->bf16, 1 rope->bf16, 2 bias->bf16, 3 bias->f32
template <int MODE>
__launch_bounds__(256, 4)
__global__ void gemm2_k(const u16* __restrict__ A, const u16* __restrict__ BT,
                        void* __restrict__ Cout, const float* __restrict__ bias,
                        const float* __restrict__ cs, const float* __restrict__ sn,
                        int Ndim, int Kdim) {
  __shared__ u16 sA[128 * 64];
  __shared__ u16 sB[128 * 64];
  const int tid = threadIdx.x;
  const int wave = tid >> 6, lane = tid & 63, quad = lane >> 4, l16 = lane & 15;
  const int wy = wave >> 1, wx = wave & 1;
  const int m0 = blockIdx.y * 128, n0 = blockIdx.x * 128;
  f32x4 acc[4][4];
  #pragma unroll
  for (int i = 0; i < 4; ++i)
    #pragma unroll
    for (int j = 0; j < 4; ++j)
      #pragma unroll
      for (int r = 0; r < 4; ++r) acc[i][j][r] = 0.f;
  const int srow = tid >> 3;        // 0..31 (32 rows per staging sweep)
  const int scol = (tid & 7) * 8;   // 0..56; LDS dest = tid*16B (wave-linear)
  for (int k0 = 0; k0 < Kdim; k0 += 64) {
    __syncthreads();
    #pragma unroll
    for (int sw = 0; sw < 4; ++sw) {
      int row = srow + 32 * sw;
      int sc = scol ^ ((row & 7) * 8);  // pre-swizzled source column
      gload16(A + (size_t)(m0 + row) * Kdim + k0 + sc, &sA[row * 64 + scol]);
      gload16(BT + (size_t)(n0 + row) * Kdim + k0 + sc, &sB[row * 64 + scol]);
    }
    __syncthreads();
    #pragma unroll
    for (int kk2 = 0; kk2 < 2; ++kk2) {
      const int cbase = (kk2 * 32 + quad * 8) ^ ((l16 & 7) * 8);
      bf16x8 af[4], bf[4];
      #pragma unroll
      for (int t = 0; t < 4; ++t) af[t] = ld8(&sA[(wy * 64 + t * 16 + l16) * 64 + cbase]);
      #pragma unroll
      for (int t = 0; t < 4; ++t) bf[t] = ld8(&sB[(wx * 64 + t * 16 + l16) * 64 + cbase]);
      #pragma unroll
      for (int i = 0; i < 4; ++i)
        #pragma unroll
        for (int j = 0; j < 4; ++j)
          acc[i][j] = MFMA16(af[i], bf[j], acc[i][j], 0, 0, 0);
    }
  }
  #pragma unroll
  for (int i = 0; i < 4; ++i) {
    #pragma unroll
    for (int j = 0; j < 4; ++j) {
      int col = n0 + wx * 64 + j * 16 + l16;
      float badd = (MODE == 2 || MODE == 3) ? bias[col] : 0.f;
      #pragma unroll
      for (int r = 0; r < 4; ++r) {
        int row = m0 + wy * 64 + i * 16 + quad * 4 + r;  // C: col=lane&15, row=quad*4+reg
        float v = acc[i][j][r] + badd;
        if (MODE == 1) {  // fused RoPE: pairs (col even, col odd) across lane^1
          float vp = __shfl_xor(v, 1);
          int n = row & (Nctx - 1);
          float c = cs[(size_t)n * Ff + col];
          float s = sn[(size_t)n * Ff + col];
          v = (l16 & 1) ? (v * c + vp * s) : (v * c - vp * s);
        }
        if (MODE == 3) ((float*)Cout)[(size_t)row * Ndim + col] = v;
        else           ((u16*)Cout)[(size_t)row * Ndim + col] = f2b(v);
      }
    }
  }
}

// ---------------- flash attention (causal, unscaled), 2 blocks/CU ----------------
// EXACT round-6/8/10 attn_k (294-295us, VGPR 256, FETCH 66MB verified 4x).
// 512 blocks x 256 thr (4 waves). K-tile staged in LDS (4x reuse across
// q-waves); V read directly from L2-resident Vt in PV (zero-reuse within a
// block). LDS ~73.5 KiB -> 2 blocks/CU; (256,1) -> 256 VGPR spill-free;
// 2 waves/SIMD x 256 VGPR = full register file, blocks cross-hide latencies.
// Measured-negative levers (do NOT re-add): setprio around MFMA (round 7:
// -33us, barrier-synced blocks starve partner staging); T13 defer-max +
// rescale-skip (round 12: +12us -- the rescale multiplies were latency-hidden
// filler; T13's compare/ballot/branch sit on the critical path in this
// 18%-VALU regime). Allocator rule (session-measured): ONLY 4-wave blocks at
// (256,1) get the 256-VGPR budget; 8-wave variants and (256,2) pin to 128 ->
// acc spills to scratch. Next lever requires per-thread state < 170 VGPR
// (3 waves/SIMD) -- needs an in-register-P rewrite (acc 128 + qf 64 = 192).
// Schedule: XCD-affine decode; zigzag qt (co-resident pairs sum to 33 units);
// lockstep ascending jt sweep -> per-head working set ~2 tiles, L2-broadcast.
__launch_bounds__(256, 1)
__global__ void attn_k(const u16* __restrict__ Q, const u16* __restrict__ K,
                       const u16* __restrict__ Vt, u16* __restrict__ Yp) {
  __shared__ u16 sK[64 * 512];   // [key][dh], phys chunk16 = (chunk+key)&63
  __shared__ u16 sP[64 * 72];
  __shared__ float sAl[64];
  __shared__ float sL[64];
  const int idx = blockIdx.x;
  const int hi = idx >> 8;
  const int bh = (idx & 7) | (hi << 3);  // XCD-affine: idx%8 pins h per XCD
  const int q_ = (idx >> 3) & 31;
  const int zig = (q_ & 1) ? (31 - (q_ >> 1)) : (q_ >> 1);
  const int qt = hi ? (31 - zig) : zig;  // pairs sum to 33 units in both pairings
  const int b = bh >> 3, h = bh & 7;
  const int q0 = qt * 64;
  const int wave = threadIdx.x >> 6, lane = threadIdx.x & 63;
  const int quad = lane >> 4, l16 = lane & 15;
  const int mq = q0 + wave * 16;  // QK^T rows for this wave
  const int wd = wave * 128;      // PV dh-slice for this wave

  bf16x8 qf[16];
  {
    const u16* qp = Q + ((size_t)(b * Nctx + mq + l16)) * Ff + h * Dh + quad * 8;
    #pragma unroll
    for (int i = 0; i < 16; ++i) qf[i] = ld8(qp + i * 32);
  }
  f32x4 acc[4][8];
  #pragma unroll
  for (int g = 0; g < 4; ++g)
    #pragma unroll
    for (int t = 0; t < 8; ++t)
      #pragma unroll
      for (int r = 0; r < 4; ++r) acc[g][t][r] = 0.f;
  float mrun[4], lrun[4];
  #pragma unroll
  for (int r = 0; r < 4; ++r) { mrun[r] = -__builtin_inff(); lrun[r] = 0.f; }

  auto stageK = [&](int j0) {
    #pragma unroll
    for (int it = 0; it < 16; ++it) {
      int row = wave * 16 + it;
      const u16* gp = K + ((size_t)(b * Nctx + j0 + row)) * Ff + h * Dh + (((lane - row) & 63) * 8);
      gload16(gp, &sK[row * 512 + lane * 8]);
    }
  };
  // V row pointer for this lane's dh rows (l16 selects row within 16-row group)
  const u16* vrow = Vt + ((size_t)(bh * Dh + wd + l16)) * Nctx;

  stageK(0);
  for (int jt = 0; jt <= qt; ++jt) {
    const int j0 = jt * 64;
    __syncthreads();  // K(jt) DMA drained; prev pv's sP reads ordered
    // --- QK^T over 64 keys ---
    f32x4 s[4];
    #pragma unroll
    for (int kg = 0; kg < 4; ++kg)
      #pragma unroll
      for (int r = 0; r < 4; ++r) s[kg][r] = 0.f;
    #pragma unroll
    for (int kk = 0; kk < 16; ++kk) {
      #pragma unroll
      for (int kg = 0; kg < 4; ++kg) {
        int key = kg * 16 + l16;
        bf16x8 bfr = ld8(&sK[key * 512 + (((kk * 4 + quad + key) & 63) * 8)]);
        s[kg] = MFMA16(qf[kk], bfr, s[kg], 0, 0, 0);
      }
    }
    // --- online softmax (mask only on diagonal tile) ---
    const bool diag = (jt == qt);
    float p[4][4], alpha[4];
    #pragma unroll
    for (int r = 0; r < 4; ++r) {
      int qrow = mq + quad * 4 + r;
      float sv[4];
      #pragma unroll
      for (int kg = 0; kg < 4; ++kg) {
        int key = j0 + kg * 16 + l16;
        sv[kg] = (diag && key > qrow) ? -__builtin_inff() : s[kg][r];
      }
      float mx = fmaxf(fmaxf(sv[0], sv[1]), fmaxf(sv[2], sv[3]));
      mx = fmaxf(mx, __shfl_xor(mx, 1));
      mx = fmaxf(mx, __shfl_xor(mx, 2));
      mx = fmaxf(mx, __shfl_xor(mx, 4));
      mx = fmaxf(mx, __shfl_xor(mx, 8));
      float mnew = fmaxf(mrun[r], mx);
      float a = __expf(mrun[r] - mnew);
      float rs = 0.f;
      #pragma unroll
      for (int kg = 0; kg < 4; ++kg) { float pe = __expf(sv[kg] - mnew); p[r][kg] = pe; rs += pe; }
      lrun[r] = lrun[r] * a + rs;
      mrun[r] = mnew;
      alpha[r] = a;
    }
    #pragma unroll
    for (int r = 0; r < 4; ++r) {
      #pragma unroll
      for (int kg = 0; kg < 4; ++kg)
        sP[(wave * 16 + quad * 4 + r) * 72 + kg * 16 + l16] = f2b(p[r][kg]);
      if (l16 == 0) sAl[wave * 16 + quad * 4 + r] = alpha[r];
    }
    __syncthreads();  // sP/sAl visible; all waves done reading sK(jt)
    if (jt < qt) stageK(j0 + 64);  // async; overlaps PV below; drained at loop top
    // --- PV for this tile: P from sP, V direct from global (L2) ---
    {
      #pragma unroll
      for (int g = 0; g < 4; ++g) {
        float a0 = sAl[g * 16 + quad * 4 + 0];
        float a1 = sAl[g * 16 + quad * 4 + 1];
        float a2 = sAl[g * 16 + quad * 4 + 2];
        float a3 = sAl[g * 16 + quad * 4 + 3];
        #pragma unroll
        for (int t = 0; t < 8; ++t) {
          acc[g][t][0] *= a0; acc[g][t][1] *= a1; acc[g][t][2] *= a2; acc[g][t][3] *= a3;
        }
      }
      bf16x8 pf[4][2];
      #pragma unroll
      for (int g = 0; g < 4; ++g)
        #pragma unroll
        for (int kk = 0; kk < 2; ++kk)
          pf[g][kk] = ld8(&sP[(g * 16 + l16) * 72 + kk * 32 + quad * 8]);
      #pragma unroll
      for (int t = 0; t < 8; ++t) {
        const u16* vp = vrow + (size_t)(t * 16) * Nctx + j0 + quad * 8;
        bf16x8 v0 = ld8(vp);
        bf16x8 v1 = ld8(vp + 32);
        #pragma unroll
        for (int g = 0; g < 4; ++g) acc[g][t] = MFMA16(pf[g][0], v0, acc[g][t], 0, 0, 0);
        #pragma unroll
        for (int g = 0; g < 4; ++g) acc[g][t] = MFMA16(pf[g][1], v1, acc[g][t], 0, 0, 0);
      }
    }
  }
  // row sums -> sL
  #pragma unroll
  for (int r = 0; r < 4; ++r) {
    float l = lrun[r];
    l += __shfl_xor(l, 1);
    l += __shfl_xor(l, 2);
    l += __shfl_xor(l, 4);
    l += __shfl_xor(l, 8);
    if (l16 == 0) sL[wave * 16 + quad * 4 + r] = l;
  }
  __syncthreads();
  #pragma unroll
  for (int g = 0; g < 4; ++g) {
    float inv[4];
    #pragma unroll
    for (int r = 0; r < 4; ++r) inv[r] = 1.f / sL[g * 16 + quad * 4 + r];
    #pragma unroll
    for (int t = 0; t < 8; ++t)
      #pragma unroll
      for (int r = 0; r < 4; ++r)
        Yp[((size_t)bh * Nctx + q0 + g * 16 + quad * 4 + r) * Dh + wd + t * 16 + l16] =
            f2b(acc[g][t][r] * inv[r]);
  }
}

// ---------------- head-sum + QuickGELU -> bf16 ----------------
__global__ void sumheads_k(const u16* __restrict__ Yp, u16* __restrict__ Ys) {
  size_t idx = (size_t)blockIdx.x * 256 + threadIdx.x;
  size_t e0 = idx * 8;
  int b = (int)(e0 >> 20);
  size_t rem = e0 & ((1u << 20) - 1);
  float s[8];
  #pragma unroll
  for (int e = 0; e < 8; ++e) s[e] = 0.f;
  #pragma unroll
  for (int h = 0; h < Hh; ++h) {
    u16x8 v = *(const u16x8*)&Yp[((size_t)(b * Hh + h) << 20) + rem];
    #pragma unroll
    for (int e = 0; e < 8; ++e) s[e] += b2f(v[e]);
  }
  u16x8 o;
  #pragma unroll
  for (int e = 0; e < 8; ++e) {
    float g = s[e] / (1.f + __expf(-1.702f * s[e]));
    o[e] = f2b(g);
  }
  *(u16x8*)&Ys[e0] = o;
}

extern "C" void kernel_launch(void* const* d_in, const int* in_sizes, int n_in,
                              void* d_out, int out_size, void* d_ws, size_t ws_size,
                              hipStream_t stream) {
  const float* x  = (const float*)d_in[0];
  const float* cs = (const float*)d_in[1];
  const float* sn = (const float*)d_in[2];
  int wbase = 4;                        // target_mask (bool tril) at idx 3, hard-coded
  if (n_in == 9) wbase = 3;
  if (wbase + 3 < n_in && in_sizes[wbase + 3] != 4096) wbase = (wbase == 4) ? 3 : 4;
  const float* Wq = (const float*)d_in[wbase + 0];
  const float* Wk = (const float*)d_in[wbase + 1];
  const float* Wv = (const float*)d_in[wbase + 2];
  const float* bv = (const float*)d_in[wbase + 3];
  const float* Wo = (const float*)d_in[wbase + 4];
  const float* bo = (const float*)d_in[wbase + 5];

  // ws layout (132.5 MiB), with aliasing:
  //  [0,32M): WqT@0, WkT@4M, WvT@8M, xb@12M  -> later reused as Vt
  //  [32,64M): Qb   [64,96M): Kb   [96,128M): Vb -> later reused as Yp
  //  [128M,+0.5M): WoT   [+0.5M,+4.5M): Ys
  char* ws = (char*)d_ws;
  const size_t MiB = 1ull << 20;
  u16* WqT = (u16*)(ws + 0 * MiB);
  u16* WkT = (u16*)(ws + 4 * MiB);
  u16* WvT = (u16*)(ws + 8 * MiB);
  u16* xb  = (u16*)(ws + 12 * MiB);
  u16* Vt  = (u16*)(ws + 0 * MiB);    // alias: weights/xb dead after QKV gemms
  u16* Qb  = (u16*)(ws + 32 * MiB);
  u16* Kb  = (u16*)(ws + 64 * MiB);
  u16* Vb  = (u16*)(ws + 96 * MiB);
  u16* Yp  = Vb;                      // alias: Vb dead after vtrans
  u16* WoT = (u16*)(ws + 128 * MiB);
  u16* Ys  = (u16*)(ws + 128 * MiB + 512 * 1024);

  dim3 tb(32, 8);
  transpose_k<<<dim3(Ff / 32, Dm / 32), tb, 0, stream>>>(Wq, WqT, Dm, Ff);
  transpose_k<<<dim3(Ff / 32, Dm / 32), tb, 0, stream>>>(Wk, WkT, Dm, Ff);
  transpose_k<<<dim3(Ff / 32, Dm / 32), tb, 0, stream>>>(Wv, WvT, Dm, Ff);
  transpose_k<<<dim3(Dm / 32, Dm / 32), tb, 0, stream>>>(Wo, WoT, Dm, Dm);
  convert_k<<<dim3(Mrows * Dm / 8 / 256), 256, 0, stream>>>(x, xb, Mrows * Dm / 8);

  gemm2_k<1><<<dim3(Ff / 128, Mrows / 128), 256, 0, stream>>>(xb, WqT, Qb, nullptr, cs, sn, Ff, Dm);
  gemm2_k<1><<<dim3(Ff / 128, Mrows / 128), 256, 0, stream>>>(xb, WkT, Kb, nullptr, cs, sn, Ff, Dm);
  gemm2_k<2><<<dim3(Ff / 128, Mrows / 128), 256, 0, stream>>>(xb, WvT, Vb, bv, nullptr, nullptr, Ff, Dm);

  vtrans_k<<<dim3(Nctx / 64, Dh / 64, Bb * Hh), 256, 0, stream>>>(Vb, Vt);

  attn_k<<<dim3(512), 256, 0, stream>>>(Qb, Kb, Vt, Yp);

  sumheads_k<<<dim3(Mrows * Dm / 8 / 256), 256, 0, stream>>>(Yp, Ys);

  gemm2_k<3><<<dim3(Dm / 128, Mrows / 128), 256, 0, stream>>>(Ys, WoT, d_out, bo, nullptr, nullptr, Dm, Dm);
}